// Round 6
// baseline (601.471 us; speedup 1.0000x reference)
//
#include <hip/hip_runtime.h>

#define V_BINS 1000001

// Kernel 0: detect whether item_seq is int64 (odd int32 words all zero) or
// int32 (odd words are random ids, essentially never all zero).
// flag = 1 -> 64-bit ids, flag = 0 -> 32-bit ids.
__global__ void detect_kernel(const unsigned int* __restrict__ w, int* __restrict__ flag) {
    __shared__ int s_any;
    if (threadIdx.x == 0) s_any = 0;
    __syncthreads();
    unsigned int o = 0;
    for (int i = threadIdx.x; i < 1024; i += blockDim.x)
        o |= w[2 * i + 1];
    if (o) atomicOr(&s_any, 1);
    __syncthreads();
    if (threadIdx.x == 0) *flag = (s_any == 0) ? 1 : 0;
}

// Kernel 1: zero the int32 count workspace and write idx half of output (f32).
__global__ void init_kernel(int* __restrict__ cnt, float* __restrict__ out) {
    int stride = gridDim.x * blockDim.x;
    for (int j = blockIdx.x * blockDim.x + threadIdx.x; j < V_BINS; j += stride) {
        cnt[j] = 0;
        out[j] = (float)j;
    }
}

// Kernel 2: histogram. Branches on detected id width. Range-guarded atomics
// so bad assumptions can never scribble outside cnt[].
__global__ void hist_kernel(const int* __restrict__ ids, int n,
                            const int* __restrict__ flag, int* __restrict__ cnt) {
    const bool wide = (*flag != 0);
    int stride = gridDim.x * blockDim.x;
    int tid = blockIdx.x * blockDim.x + threadIdx.x;
    const int4* p = (const int4*)ids;
    if (!wide) {
        // int32 ids: int4 = 4 ids
        int n4 = n >> 2;
        for (int j = tid; j < n4; j += stride) {
            int4 v = p[j];
            if ((unsigned)v.x < (unsigned)V_BINS) atomicAdd(&cnt[v.x], 1);
            if ((unsigned)v.y < (unsigned)V_BINS) atomicAdd(&cnt[v.y], 1);
            if ((unsigned)v.z < (unsigned)V_BINS) atomicAdd(&cnt[v.z], 1);
            if ((unsigned)v.w < (unsigned)V_BINS) atomicAdd(&cnt[v.w], 1);
        }
        for (int j = (n4 << 2) + tid; j < n; j += stride) {
            int id = ids[j];
            if ((unsigned)id < (unsigned)V_BINS) atomicAdd(&cnt[id], 1);
        }
    } else {
        // int64 ids (little-endian, values < 2^31): int4 = 2 ids, low words x/z
        int n2 = n >> 1;  // number of int4 chunks covering 2*n2 ids
        for (int j = tid; j < n2; j += stride) {
            int4 v = p[j];
            if ((unsigned)v.x < (unsigned)V_BINS) atomicAdd(&cnt[v.x], 1);
            if ((unsigned)v.z < (unsigned)V_BINS) atomicAdd(&cnt[v.z], 1);
        }
        for (int j = (n2 << 1) + tid; j < n; j += stride) {
            int id = ids[2 * j];
            if ((unsigned)id < (unsigned)V_BINS) atomicAdd(&cnt[id], 1);
        }
    }
}

// Kernel 3: counts -> f32 into second half of output.
__global__ void finalize_kernel(const int* __restrict__ cnt, float* __restrict__ out) {
    int stride = gridDim.x * blockDim.x;
    for (int j = blockIdx.x * blockDim.x + threadIdx.x; j < V_BINS; j += stride) {
        out[V_BINS + j] = (float)cnt[j];
    }
}

extern "C" void kernel_launch(void* const* d_in, const int* in_sizes, int n_in,
                              void* d_out, int out_size, void* d_ws, size_t ws_size,
                              hipStream_t stream) {
    const int* item_seq = (const int*)d_in[0];   // ids in [0, V_BINS), width detected on-device
    // d_in[1] = ones (float32, all 1.0f) — histogram of +1s, not needed.
    float* out = (float*)d_out;                  // [idx (f32) ; cnt (f32)]
    int* flag = (int*)d_ws;                      // 1 int
    int* cnt = (int*)d_ws + 16;                  // 4*V_BINS bytes, 64B-aligned
    int n = in_sizes[0];                         // 13,107,200 logical ids

    const int BLK = 256;
    const int GRID = 2048;  // 256 CUs * 8 blocks, grid-stride

    detect_kernel<<<1, 256, 0, stream>>>((const unsigned int*)item_seq, flag);
    init_kernel<<<GRID, BLK, 0, stream>>>(cnt, out);
    hist_kernel<<<GRID, BLK, 0, stream>>>(item_seq, n, flag, cnt);
    finalize_kernel<<<GRID, BLK, 0, stream>>>(cnt, out);
}

// Round 7
// 599.112 us; speedup vs baseline: 1.0039x; 1.0039x over previous
//
#include <hip/hip_runtime.h>

#define V_BINS 1000001

__device__ __forceinline__ void acc(int* __restrict__ cnt, int id) {
    if ((unsigned)id < (unsigned)V_BINS) atomicAdd(&cnt[id], 1);
}

// Kernel 1: zero cnt workspace, write idx half of output (f32), and (block 0)
// detect id width: odd int32 words all zero -> int64 ids (flag=1).
__global__ void init_kernel(int* __restrict__ cnt, float* __restrict__ out,
                            const unsigned int* __restrict__ w, int* __restrict__ flag) {
    if (blockIdx.x == 0) {
        __shared__ int s_any;
        if (threadIdx.x == 0) s_any = 0;
        __syncthreads();
        unsigned int o = 0;
        for (int i = threadIdx.x; i < 1024; i += blockDim.x) o |= w[2 * i + 1];
        if (o) atomicOr(&s_any, 1);
        __syncthreads();
        if (threadIdx.x == 0) *flag = (s_any == 0) ? 1 : 0;
    }
    int stride = gridDim.x * blockDim.x;
    for (int j = blockIdx.x * blockDim.x + threadIdx.x; j < V_BINS; j += stride) {
        cnt[j] = 0;
        out[j] = (float)j;
    }
}

// Kernel 2: histogram, 4x-unrolled independent loads to deepen the in-flight
// atomic queue (discriminates latency-bound vs atomic-pipe-bound).
__global__ void hist_kernel(const int* __restrict__ ids, int n,
                            const int* __restrict__ flag, int* __restrict__ cnt) {
    const bool wide = (*flag != 0);
    const int gstride = gridDim.x * blockDim.x;
    const int tid = blockIdx.x * blockDim.x + threadIdx.x;
    const int4* p = (const int4*)ids;
    if (wide) {
        // int64 ids: int4 = 2 ids (low words x, z)
        int n2 = n >> 1;  // # int4 chunks
        int j = tid;
        int nq = n2 / (4 * gstride);
        for (int q = 0; q < nq; ++q) {
            int4 a = p[j];
            int4 b = p[j + gstride];
            int4 c = p[j + 2 * gstride];
            int4 d = p[j + 3 * gstride];
            acc(cnt, a.x); acc(cnt, a.z);
            acc(cnt, b.x); acc(cnt, b.z);
            acc(cnt, c.x); acc(cnt, c.z);
            acc(cnt, d.x); acc(cnt, d.z);
            j += 4 * gstride;
        }
        for (; j < n2; j += gstride) {
            int4 v = p[j];
            acc(cnt, v.x); acc(cnt, v.z);
        }
        // odd trailing id (n odd): ids[2*(n-1)]
        if (tid == 0 && (n & 1)) acc(cnt, ids[2 * (n - 1)]);
    } else {
        // int32 ids: int4 = 4 ids
        int n4 = n >> 2;
        int j = tid;
        int nq = n4 / (4 * gstride);
        for (int q = 0; q < nq; ++q) {
            int4 a = p[j];
            int4 b = p[j + gstride];
            int4 c = p[j + 2 * gstride];
            int4 d = p[j + 3 * gstride];
            acc(cnt, a.x); acc(cnt, a.y); acc(cnt, a.z); acc(cnt, a.w);
            acc(cnt, b.x); acc(cnt, b.y); acc(cnt, b.z); acc(cnt, b.w);
            acc(cnt, c.x); acc(cnt, c.y); acc(cnt, c.z); acc(cnt, c.w);
            acc(cnt, d.x); acc(cnt, d.y); acc(cnt, d.z); acc(cnt, d.w);
            j += 4 * gstride;
        }
        for (; j < n4; j += gstride) {
            int4 v = p[j];
            acc(cnt, v.x); acc(cnt, v.y); acc(cnt, v.z); acc(cnt, v.w);
        }
        for (int t = (n4 << 2) + tid; t < n; t += gstride) acc(cnt, ids[t]);
    }
}

// Kernel 3: counts -> f32 into second half of output (4B/lane coalesced).
__global__ void finalize_kernel(const int* __restrict__ cnt, float* __restrict__ out) {
    int stride = gridDim.x * blockDim.x;
    for (int j = blockIdx.x * blockDim.x + threadIdx.x; j < V_BINS; j += stride) {
        out[V_BINS + j] = (float)cnt[j];
    }
}

extern "C" void kernel_launch(void* const* d_in, const int* in_sizes, int n_in,
                              void* d_out, int out_size, void* d_ws, size_t ws_size,
                              hipStream_t stream) {
    const int* item_seq = (const int*)d_in[0];   // ids, width detected on-device (int64 expected)
    float* out = (float*)d_out;                  // [idx f32 ; cnt f32]
    int* flag = (int*)d_ws;                      // 1 int
    int* cnt = (int*)d_ws + 16;                  // 4*V_BINS bytes, 64B-aligned
    int n = in_sizes[0];                         // 13,107,200 logical ids

    const int BLK = 256;
    const int GRID = 2048;  // 256 CUs * 8 blocks

    init_kernel<<<GRID, BLK, 0, stream>>>(cnt, out, (const unsigned int*)item_seq, flag);
    hist_kernel<<<GRID, BLK, 0, stream>>>(item_seq, n, flag, cnt);
    finalize_kernel<<<GRID, BLK, 0, stream>>>(cnt, out);
}